// Round 1
// 295.708 us; speedup vs baseline: 1.0765x; 1.0765x over previous
//
#include <hip/hip_runtime.h>

// ---------------------------------------------------------------------------
// MultiHeadAttention, fp32 in/out. 4-kernel pipeline:
//   prep      : Wqkv^T/Wout^T transpose+split-bf16, x split-bf16 (fused)
//   qkv_gemm8 : 256x192 split-bf16 MFMA, 8-phase schedule (T3/T4/T5 + XCD
//               swizzle), global_load_lds double-buffer; scatters Q,K,Vt bf16
//   attn      : transposed-score flash (S^T=K.Q^T, 32x32x16), full-seq,
//               lane-scalar softmax, writes split-bf16 ctx directly
//   out_gemm  : 128x128 split-bf16 MFMA -> fp32 out
// ---------------------------------------------------------------------------

typedef __attribute__((ext_vector_type(8)))  short short8;
typedef __attribute__((ext_vector_type(4)))  short short4v;
typedef __attribute__((ext_vector_type(8)))  float float8;
typedef __attribute__((ext_vector_type(4)))  float f32x4;
typedef __attribute__((ext_vector_type(16))) float f32x16;
typedef __attribute__((ext_vector_type(4)))  int   int4v;

#define D_MODEL 1024
#define NHEAD   16
#define HD      64
#define SEQ     2048
#define N3      (3*D_MODEL)
#define MB      (1024*1024)

static __device__ __forceinline__ float bf2f(short s) {
    unsigned u = ((unsigned)(unsigned short)s) << 16;
    return __builtin_bit_cast(float, u);
}
static __device__ __forceinline__ short f2bf(float f) {
    unsigned u = __builtin_bit_cast(unsigned, f);
    u = (u + 0x7fff + ((u >> 16) & 1)) >> 16;   // RNE
    return (short)u;
}
static __device__ __forceinline__ unsigned pkbf(float a, float b) {
    unsigned ua = __builtin_bit_cast(unsigned, a);
    ua = (ua + 0x7fff + ((ua >> 16) & 1)) >> 16;
    unsigned ub = __builtin_bit_cast(unsigned, b);
    ub = (ub + 0x7fff + ((ub >> 16) & 1)) & 0xffff0000u;
    return ua | ub;
}
static __device__ __forceinline__ void gl16(const short* g, short* l) {
    __builtin_amdgcn_global_load_lds(
        (const __attribute__((address_space(1))) unsigned int*)g,
        (__attribute__((address_space(3))) unsigned int*)l, 16, 0, 0);
}

// ---------------------------------------------------------------------------
// prep: blocks [0,2048) split x; [2048,5120) transpose-split Wqkv;
//       [5120,6144) transpose-split Wout.
// ---------------------------------------------------------------------------
__global__ __launch_bounds__(256) void prep(
    const float* __restrict__ x, const float* __restrict__ Wqkv,
    const float* __restrict__ Wout,
    short* __restrict__ Xh, short* __restrict__ Xl,
    short* __restrict__ Wh, short* __restrict__ Wl,
    short* __restrict__ Woh, short* __restrict__ Wol)
{
    __shared__ float tile[32][33];
    const int bid = blockIdx.x;
    const int tid = threadIdx.x;

    if (bid < 2048) {                        // ---- split x ----
        const int i = (bid * 256 + tid) * 8;
        const float8 v = *(const float8*)&x[i];
        short8 h, l;
#pragma unroll
        for (int j = 0; j < 8; ++j) {
            h[j] = f2bf(v[j]);
            l[j] = f2bf(v[j] - bf2f(h[j]));
        }
        *(short8*)&Xh[i] = h;
        *(short8*)&Xl[i] = l;
        return;
    }

    // ---- transpose + split a weight matrix ----
    const float* in; short *hi, *lo; int K, N, bx, by;
    if (bid < 5120) {
        const int b2 = bid - 2048;
        in = Wqkv; hi = Wh; lo = Wl; K = D_MODEL; N = N3;
        bx = b2 % 96; by = b2 / 96;
    } else {
        const int b3 = bid - 5120;
        in = Wout; hi = Woh; lo = Wol; K = D_MODEL; N = D_MODEL;
        bx = b3 & 31; by = b3 >> 5;
    }
    const int n0 = bx * 32, k0 = by * 32;
    const int tx = tid & 31, ty = tid >> 5;
#pragma unroll
    for (int i = 0; i < 4; ++i)
        tile[ty + 8*i][tx] = in[(k0 + ty + 8*i) * N + (n0 + tx)];
    __syncthreads();
#pragma unroll
    for (int i = 0; i < 4; ++i) {
        const float v  = tile[tx][ty + 8*i];
        const short vh = f2bf(v);
        const short vl = f2bf(v - bf2f(vh));
        const int idx  = (n0 + ty + 8*i) * K + (k0 + tx);
        hi[idx] = vh;
        lo[idx] = vl;
    }
}

// ---------------------------------------------------------------------------
// QKV GEMM, 8-phase schedule. BM=256 BN=192 BK=32, 512 threads (8 waves 2Mx4N),
// per-wave output 128x48. LDS: 2 x 56KB buffers, linear layout (gl16-direct,
// conflict-free contiguous ds_read). Prefetch tile t+1 issued at phase 0 of
// tile t; single vmcnt(0) drain per K-tile at phase 3 (loads in flight across
// all 8 intra-tile barriers). grid = 256 blocks = 1/CU; block-col == head.
// ---------------------------------------------------------------------------
#define QBUF_SH 28672          // shorts per LDS buffer (56KB)
#define OFF_AL  8192
#define OFF_BH  16384
#define OFF_BL  22528

__global__ __launch_bounds__(512, 2) void qkv_gemm8(
    const short* __restrict__ Xh, const short* __restrict__ Xl,
    const short* __restrict__ Bh, const short* __restrict__ Bl,
    const float* __restrict__ bias,
    short* __restrict__ Qo, short* __restrict__ Ko, short* __restrict__ Vt)
{
    __shared__ __attribute__((aligned(16))) short smem[2 * QBUF_SH];

    const int tid  = threadIdx.x;
    const int wave = tid >> 6, lane = tid & 63;
    const int q4 = lane >> 4, l16 = lane & 15;
    const int wr = wave >> 2, wc = wave & 3;

    // XCD-aware swizzle (256 blocks, 8 XCDs -> 32 contiguous per XCD;
    // decompose so each XCD holds 2 B-panels (L2-resident), streams A).
    const int flat = blockIdx.x;
    const int sw = (flat & 7) * 32 + (flat >> 3);
    const int mt = sw & 15, nt = sw >> 4;
    const int m0 = mt * 256, n0 = nt * 192;

    // staging map: flat chunk id = j*512+tid over [Ah 1024][Al 1024][Bh 768][Bl 768]
    const short* srcp[7];
#pragma unroll
    for (int j = 0; j < 7; ++j) {
        const int id = j * 512 + tid;
        const short* s;
        if (id < 1024)      { s = &Xh[(size_t)(m0 + (id >> 2)) * D_MODEL + (id & 3) * 8]; }
        else if (id < 2048) { const int c = id - 1024; s = &Xl[(size_t)(m0 + (c >> 2)) * D_MODEL + (c & 3) * 8]; }
        else if (id < 2816) { const int c = id - 2048; s = &Bh[(size_t)(n0 + (c >> 2)) * D_MODEL + (c & 3) * 8]; }
        else                { const int c = id - 2816; s = &Bl[(size_t)(n0 + (c >> 2)) * D_MODEL + (c & 3) * 8]; }
        srcp[j] = s;
    }

    auto stage = [&](int b) {
#pragma unroll
        for (int j = 0; j < 7; ++j) {
            gl16(srcp[j], smem + b * QBUF_SH + (j * 512 + tid) * 8);
            srcp[j] += 32;                  // advance one K-tile
        }
    };

    f32x4 acc[8][3];
#pragma unroll
    for (int i = 0; i < 8; ++i)
#pragma unroll
        for (int j = 0; j < 3; ++j) acc[i][j] = (f32x4){0.f, 0.f, 0.f, 0.f};

    stage(0);
    asm volatile("s_waitcnt vmcnt(0)" ::: "memory");
    __builtin_amdgcn_s_barrier();

    for (int t = 0; t < 32; ++t) {
        const int cur = t & 1;
        const short* base = smem + cur * QBUF_SH;
        const short* Ah_s = base;
        const short* Al_s = base + OFF_AL;
        const short* Bh_s = base + OFF_BH;
        const short* Bl_s = base + OFF_BL;

        short8 bhf[3], blf[3];
#pragma unroll
        for (int p = 0; p < 4; ++p) {
            // ds-load this phase's A sub-tiles (2 M-frags x hi/lo)
            const int r0 = (wr * 128 + (2*p)   * 16 + l16) * 32 + q4 * 8;
            const int r1 = (wr * 128 + (2*p+1) * 16 + l16) * 32 + q4 * 8;
            const short8 a0h = *(const short8*)(Ah_s + r0);
            const short8 a0l = *(const short8*)(Al_s + r0);
            const short8 a1h = *(const short8*)(Ah_s + r1);
            const short8 a1l = *(const short8*)(Al_s + r1);
            if (p == 0) {
#pragma unroll
                for (int n = 0; n < 3; ++n) {
                    const int rb = (wc * 48 + n * 16 + l16) * 32 + q4 * 8;
                    bhf[n] = *(const short8*)(Bh_s + rb);
                    blf[n] = *(const short8*)(Bl_s + rb);
                }
                if (t < 31) stage(cur ^ 1);   // prefetch next K-tile (stays in
                                              // flight across 8 barriers)
            }
            __builtin_amdgcn_s_barrier();
            asm volatile("s_waitcnt lgkmcnt(0)" ::: "memory");
            __builtin_amdgcn_sched_barrier(0);
            __builtin_amdgcn_s_setprio(1);
#pragma unroll
            for (int n = 0; n < 3; ++n) {
                acc[2*p][n]   = __builtin_amdgcn_mfma_f32_16x16x32_bf16(a0h, bhf[n], acc[2*p][n],   0, 0, 0);
                acc[2*p][n]   = __builtin_amdgcn_mfma_f32_16x16x32_bf16(a0h, blf[n], acc[2*p][n],   0, 0, 0);
                acc[2*p][n]   = __builtin_amdgcn_mfma_f32_16x16x32_bf16(a0l, bhf[n], acc[2*p][n],   0, 0, 0);
                acc[2*p+1][n] = __builtin_amdgcn_mfma_f32_16x16x32_bf16(a1h, bhf[n], acc[2*p+1][n], 0, 0, 0);
                acc[2*p+1][n] = __builtin_amdgcn_mfma_f32_16x16x32_bf16(a1h, blf[n], acc[2*p+1][n], 0, 0, 0);
                acc[2*p+1][n] = __builtin_amdgcn_mfma_f32_16x16x32_bf16(a1l, bhf[n], acc[2*p+1][n], 0, 0, 0);
            }
            __builtin_amdgcn_s_setprio(0);
            if (p == 3) asm volatile("s_waitcnt vmcnt(0)" ::: "memory");
            __builtin_amdgcn_s_barrier();
        }
    }

    // epilogue: scatter Q (pre-scaled), K, Vt
    const float SCALE_Q = 0.125f * 1.4426950408889634f;
#pragma unroll
    for (int tj = 0; tj < 3; ++tj) {
        const int jj = wc * 48 + tj * 16 + l16;   // 0..191 within head
        const int n  = nt * 192 + jj;
        const float bv = bias[n];
#pragma unroll
        for (int ti = 0; ti < 8; ++ti) {
            const int mb = m0 + wr * 128 + ti * 16 + q4 * 4;
            const int b = mb >> 11;
            const int s = mb & 2047;
            const int bh_ = b * NHEAD + nt;
            if (jj >= 128) {                      // Vt: s is fast axis -> short4
                short4v v4;
#pragma unroll
                for (int r = 0; r < 4; ++r) v4[r] = f2bf(acc[ti][tj][r] + bv);
                *(short4v*)&Vt[(bh_ * HD + (jj - 128)) * SEQ + s] = v4;
            } else if (jj < 64) {
#pragma unroll
                for (int r = 0; r < 4; ++r)
                    Qo[(bh_ * SEQ + s + r) * HD + jj] = f2bf((acc[ti][tj][r] + bv) * SCALE_Q);
            } else {
#pragma unroll
                for (int r = 0; r < 4; ++r)
                    Ko[(bh_ * SEQ + s + r) * HD + (jj - 64)] = f2bf(acc[ti][tj][r] + bv);
            }
        }
    }
}

// ---------------------------------------------------------------------------
// Transposed-score flash attention, full seq per block.
// Grid (32 bh, 16 qb); 4 waves x 32 queries. Writes split-bf16 ctx.
// ---------------------------------------------------------------------------
__global__ __launch_bounds__(256, 4) void attn_tscore(
    const short* __restrict__ Q, const short* __restrict__ K,
    const short* __restrict__ Vt,
    short* __restrict__ Ch, short* __restrict__ Cl)
{
    __shared__ __attribute__((aligned(16))) char smem[34816];
    short (*Ks)[72] = (short(*)[72])smem;                 // [32 key][64 d]
    short (*Vs)[40] = (short(*)[40])(smem + 4608);        // [64 d][32 key]

    const int bh = blockIdx.x;                // 0..31
    const int qb = blockIdx.y;                // 0..15
    const int bi = bh >> 4, hi_ = bh & 15;

    const short* Qp  = Q  + bh * SEQ * HD;
    const short* Kp  = K  + bh * SEQ * HD;
    const short* Vtp = Vt + bh * HD * SEQ;

    const int tid  = threadIdx.x;
    const int wave = tid >> 6, lane = tid & 63;
    const int l5 = lane & 31, hf = lane >> 5;
    const int q0w = qb * 128 + wave * 32;

    short8 qf[4];
#pragma unroll
    for (int c = 0; c < 4; ++c)
        qf[c] = *(const short8*)&Qp[(q0w + l5) * HD + c * 16 + hf * 8];

    f32x16 oacc0 = (f32x16)(0.f), oacc1 = (f32x16)(0.f);
    float m = -1.0e30f, l = 0.f;

    const int sKr = tid >> 3, sKc = (tid & 7) * 8;
    const int sVr = tid >> 2, sVc = (tid & 3) * 8;

    for (int kc = 0; kc < 64; ++kc) {
        const int kbase = kc * 32;
        __syncthreads();
        *(short8*)&Ks[sKr][sKc] = *(const short8*)&Kp[(kbase + sKr) * HD + sKc];
        *(short8*)&Vs[sVr][sVc] = *(const short8*)&Vtp[sVr * SEQ + kbase + sVc];
        __syncthreads();

        f32x16 sacc = (f32x16)(0.f);
#pragma unroll
        for (int c = 0; c < 4; ++c) {
            const short8 ka = *(const short8*)&Ks[l5][c * 16 + hf * 8];
            sacc = __builtin_amdgcn_mfma_f32_32x32x16_bf16(ka, qf[c], sacc, 0, 0, 0);
        }

        float a0 = fmaxf(sacc[0], sacc[8]),  a1 = fmaxf(sacc[1], sacc[9]);
        float a2 = fmaxf(sacc[2], sacc[10]), a3 = fmaxf(sacc[3], sacc[11]);
        float a4 = fmaxf(sacc[4], sacc[12]), a5 = fmaxf(sacc[5], sacc[13]);
        float a6 = fmaxf(sacc[6], sacc[14]), a7 = fmaxf(sacc[7], sacc[15]);
        a0 = fmaxf(a0, a4); a1 = fmaxf(a1, a5); a2 = fmaxf(a2, a6); a3 = fmaxf(a3, a7);
        a0 = fmaxf(fmaxf(a0, a1), fmaxf(a2, a3));
        a0 = fmaxf(a0, __shfl_xor(a0, 32, 64));
        const float mnew  = fmaxf(m, a0);
        const float alpha = exp2f(m - mnew);

        float p[16];
#pragma unroll
        for (int i = 0; i < 16; ++i) p[i] = exp2f(sacc[i] - mnew);

        float s0 = p[0]+p[8], s1 = p[1]+p[9], s2 = p[2]+p[10], s3 = p[3]+p[11];
        float s4 = p[4]+p[12], s5 = p[5]+p[13], s6 = p[6]+p[14], s7 = p[7]+p[15];
        s0 += s4; s1 += s5; s2 += s6; s3 += s7;
        float rs = (s0 + s1) + (s2 + s3);
        rs += __shfl_xor(rs, 32, 64);
        l = l * alpha + rs;
        m = mnew;

#pragma unroll
        for (int i = 0; i < 16; ++i) { oacc0[i] *= alpha; oacc1[i] *= alpha; }

        unsigned u0 = pkbf(p[0],  p[1]),  u1 = pkbf(p[2],  p[3]);
        unsigned u2 = pkbf(p[4],  p[5]),  u3 = pkbf(p[6],  p[7]);
        unsigned u4 = pkbf(p[8],  p[9]),  u5 = pkbf(p[10], p[11]);
        unsigned u6 = pkbf(p[12], p[13]), u7 = pkbf(p[14], p[15]);
        const unsigned x0 = __shfl_xor(u0, 32, 64), x1 = __shfl_xor(u1, 32, 64);
        const unsigned x2 = __shfl_xor(u2, 32, 64), x3 = __shfl_xor(u3, 32, 64);
        const unsigned x4 = __shfl_xor(u4, 32, 64), x5 = __shfl_xor(u5, 32, 64);
        const unsigned x6 = __shfl_xor(u6, 32, 64), x7 = __shfl_xor(u7, 32, 64);
        int4v pb0 = (int4v){ (int)(hf ? x2 : u0), (int)(hf ? x3 : u1),
                             (int)(hf ? u2 : x0), (int)(hf ? u3 : x1) };
        int4v pb1 = (int4v){ (int)(hf ? x6 : u4), (int)(hf ? x7 : u5),
                             (int)(hf ? u6 : x4), (int)(hf ? u7 : x5) };
        const short8 pbf0 = __builtin_bit_cast(short8, pb0);
        const short8 pbf1 = __builtin_bit_cast(short8, pb1);

        {
            const short8 va00 = *(const short8*)&Vs[l5][hf * 8];
            const short8 va01 = *(const short8*)&Vs[l5][16 + hf * 8];
            oacc0 = __builtin_amdgcn_mfma_f32_32x32x16_bf16(va00, pbf0, oacc0, 0, 0, 0);
            oacc0 = __builtin_amdgcn_mfma_f32_32x32x16_bf16(va01, pbf1, oacc0, 0, 0, 0);
            const short8 va10 = *(const short8*)&Vs[32 + l5][hf * 8];
            const short8 va11 = *(const short8*)&Vs[32 + l5][16 + hf * 8];
            oacc1 = __builtin_amdgcn_mfma_f32_32x32x16_bf16(va10, pbf0, oacc1, 0, 0, 0);
            oacc1 = __builtin_amdgcn_mfma_f32_32x32x16_bf16(va11, pbf1, oacc1, 0, 0, 0);
        }
    }

    // normalize (lane-scalar) then LDS transpose + split-bf16 ctx write
    const float inv = 1.0f / l;
#pragma unroll
    for (int i = 0; i < 16; ++i) { oacc0[i] *= inv; oacc1[i] *= inv; }

    __syncthreads();
    float (*epi)[68] = (float(*)[68])(smem + wave * 8704);
#pragma unroll
    for (int r = 0; r < 16; ++r) {
        const int d = (r & 3) + 8 * (r >> 2) + 4 * hf;
        epi[l5][d]      = oacc0[r];
        epi[l5][32 + d] = oacc1[r];
    }
    __builtin_amdgcn_s_waitcnt(0);
#pragma unroll
    for (int pass = 0; pass < 8; ++pass) {
        const int row = pass * 4 + (lane >> 4);
        const int col = (lane & 15) * 4;
        const float4 v = *(const float4*)&epi[row][col];
        const float o[4] = {v.x, v.y, v.z, v.w};
        short4v hh, ll;
#pragma unroll
        for (int i = 0; i < 4; ++i) {
            hh[i] = f2bf(o[i]);
            ll[i] = f2bf(o[i] - bf2f(hh[i]));
        }
        const size_t co = ((size_t)(bi * SEQ + q0w + row)) * D_MODEL + hi_ * HD + col;
        *(short4v*)&Ch[co] = hh;
        *(short4v*)&Cl[co] = ll;
    }
}

// ---------------------------------------------------------------------------
// Output GEMM, 128x128 tile, global_load_lds, split-bf16 -> fp32 out.
// ---------------------------------------------------------------------------
__global__ __launch_bounds__(256) void out_gemm128(
    const short* __restrict__ Ah, const short* __restrict__ Al,
    const short* __restrict__ Bh, const short* __restrict__ Bl,
    const float* __restrict__ bias, float* __restrict__ out)
{
    __shared__ short AhS[128*32], AlS[128*32], BhS[128*32], BlS[128*32];

    const int tid  = threadIdx.x;
    const int wave = tid >> 6, lane = tid & 63;
    const int q4 = lane >> 4, l16 = lane & 15;
    const int m0 = blockIdx.y * 128, n0 = blockIdx.x * 128;
    const int rw = (wave & 1) * 64, cw = (wave >> 1) * 64;
    const int trow = tid >> 2;
    const int tcol = (tid & 3) * 8;

    f32x4 acc[4][4];
#pragma unroll
    for (int i = 0; i < 4; ++i)
#pragma unroll
        for (int j = 0; j < 4; ++j) acc[i][j] = (f32x4){0.f, 0.f, 0.f, 0.f};

    for (int kt = 0; kt < D_MODEL; kt += 32) {
        gl16(&Ah[(m0 + trow) * D_MODEL + kt + tcol],      AhS + tid * 8);
        gl16(&Ah[(m0 + 64 + trow) * D_MODEL + kt + tcol], AhS + 2048 + tid * 8);
        gl16(&Al[(m0 + trow) * D_MODEL + kt + tcol],      AlS + tid * 8);
        gl16(&Al[(m0 + 64 + trow) * D_MODEL + kt + tcol], AlS + 2048 + tid * 8);
        gl16(&Bh[(n0 + trow) * D_MODEL + kt + tcol],      BhS + tid * 8);
        gl16(&Bh[(n0 + 64 + trow) * D_MODEL + kt + tcol], BhS + 2048 + tid * 8);
        gl16(&Bl[(n0 + trow) * D_MODEL + kt + tcol],      BlS + tid * 8);
        gl16(&Bl[(n0 + 64 + trow) * D_MODEL + kt + tcol], BlS + 2048 + tid * 8);
        __syncthreads();

        short8 ah[4], al[4], bh[4], bl[4];
#pragma unroll
        for (int t = 0; t < 4; ++t) {
            ah[t] = *(const short8*)&AhS[(rw + t * 16 + l16) * 32 + q4 * 8];
            al[t] = *(const short8*)&AlS[(rw + t * 16 + l16) * 32 + q4 * 8];
            bh[t] = *(const short8*)&BhS[(cw + t * 16 + l16) * 32 + q4 * 8];
            bl[t] = *(const short8*)&BlS[(cw + t * 16 + l16) * 32 + q4 * 8];
        }
#pragma unroll
        for (int ti = 0; ti < 4; ++ti)
#pragma unroll
            for (int tj = 0; tj < 4; ++tj) {
                acc[ti][tj] = __builtin_amdgcn_mfma_f32_16x16x32_bf16(ah[ti], bh[tj], acc[ti][tj], 0, 0, 0);
                acc[ti][tj] = __builtin_amdgcn_mfma_f32_16x16x32_bf16(ah[ti], bl[tj], acc[ti][tj], 0, 0, 0);
                acc[ti][tj] = __builtin_amdgcn_mfma_f32_16x16x32_bf16(al[ti], bh[tj], acc[ti][tj], 0, 0, 0);
            }
        __syncthreads();
    }

#pragma unroll
    for (int tj = 0; tj < 4; ++tj) {
        const int n = n0 + cw + tj * 16 + l16;
        const float bv = bias[n];
#pragma unroll
        for (int ti = 0; ti < 4; ++ti) {
            const int mb = m0 + rw + ti * 16 + q4 * 4;
#pragma unroll
            for (int r = 0; r < 4; ++r)
                out[(mb + r) * D_MODEL + n] = acc[ti][tj][r] + bv;
        }
    }
}

// ---------------------------------------------------------------------------
extern "C" void kernel_launch(void* const* d_in, const int* in_sizes, int n_in,
                              void* d_out, int out_size, void* d_ws, size_t ws_size,
                              hipStream_t stream)
{
    const float* x    = (const float*)d_in[0];
    const float* Wqkv = (const float*)d_in[1];
    const float* bqkv = (const float*)d_in[2];
    const float* Wout = (const float*)d_in[3];
    const float* bout = (const float*)d_in[4];
    float* out = (float*)d_out;

    char* ws = (char*)d_ws;
    short* Qb  = (short*)(ws);                //  8 MB [32][2048][64] (pre-scaled)
    short* Kb  = (short*)(ws +  8*MB);        //  8 MB
    short* Vtb = (short*)(ws + 16*MB);        //  8 MB [32][64][2048]
    short* Woh = (short*)(ws + 24*MB);        //  2 MB Wout^T hi
    short* Wol = (short*)(ws + 26*MB);        //  2 MB Wout^T lo
    short* Ch  = (short*)(ws + 28*MB);        //  8 MB ctx hi
    short* Cl  = (short*)(ws + 36*MB);        //  8 MB ctx lo
    short* Xh  = (short*)(ws + 44*MB);        //  8 MB x hi
    short* Xl  = (short*)(ws + 52*MB);        //  8 MB x lo
    short* Wh  = (short*)(ws + 60*MB);        //  6 MB Wqkv^T hi
    short* Wl  = (short*)(ws + 66*MB);        //  6 MB Wqkv^T lo (end 72 MB)

    prep<<<6144, 256, 0, stream>>>(x, Wqkv, Wout, Xh, Xl, Wh, Wl, Woh, Wol);
    qkv_gemm8<<<dim3(256), 512, 0, stream>>>(Xh, Xl, Wh, Wl, bqkv, Qb, Kb, Vtb);
    attn_tscore<<<dim3(32, 16), 256, 0, stream>>>(Qb, Kb, Vtb, Ch, Cl);
    out_gemm128<<<dim3(8, 32), 256, 0, stream>>>(Ch, Cl, Woh, Wol, bout, out);
}

// Round 2
// 280.125 us; speedup vs baseline: 1.1363x; 1.0556x over previous
//
#include <hip/hip_runtime.h>

// ---------------------------------------------------------------------------
// MultiHeadAttention, fp32 in/out. 4-kernel pipeline:
//   prep      : Wqkv^T/Wout^T transpose+split-bf16, x split-bf16 (fused)
//   qkv_gemm8 : 256x192 split-bf16 MFMA, 8-phase schedule (T3/T4/T5 + XCD
//               swizzle), global_load_lds double-buffer; scatters Q,K,Vt bf16
//   attn      : transposed-score flash (S^T=K.Q^T, 32x32x16), KVBLK=64,
//               double-buffered K/V LDS with async reg-staging (T14),
//               hw cvt_pk P-pack, defer-max (T13); split-bf16 ctx out
//   out_gemm  : 128x128 split-bf16 MFMA -> fp32 out
// ---------------------------------------------------------------------------

typedef __attribute__((ext_vector_type(8)))  short short8;
typedef __attribute__((ext_vector_type(4)))  short short4v;
typedef __attribute__((ext_vector_type(8)))  float float8;
typedef __attribute__((ext_vector_type(4)))  float f32x4;
typedef __attribute__((ext_vector_type(16))) float f32x16;
typedef __attribute__((ext_vector_type(4)))  int   int4v;

#define D_MODEL 1024
#define NHEAD   16
#define HD      64
#define SEQ     2048
#define N3      (3*D_MODEL)
#define MB      (1024*1024)

static __device__ __forceinline__ float bf2f(short s) {
    unsigned u = ((unsigned)(unsigned short)s) << 16;
    return __builtin_bit_cast(float, u);
}
static __device__ __forceinline__ short f2bf(float f) {
    unsigned u = __builtin_bit_cast(unsigned, f);
    u = (u + 0x7fff + ((u >> 16) & 1)) >> 16;   // RNE
    return (short)u;
}
static __device__ __forceinline__ unsigned pkbf(float a, float b) {
    unsigned ua = __builtin_bit_cast(unsigned, a);
    ua = (ua + 0x7fff + ((ua >> 16) & 1)) >> 16;
    unsigned ub = __builtin_bit_cast(unsigned, b);
    ub = (ub + 0x7fff + ((ub >> 16) & 1)) & 0xffff0000u;
    return ua | ub;
}
// hardware packed f32->bf16 (RNE), 1 instr vs ~5 for pkbf
static __device__ __forceinline__ unsigned cvtpk(float a, float b) {
    unsigned r;
    asm("v_cvt_pk_bf16_f32 %0, %1, %2" : "=v"(r) : "v"(a), "v"(b));
    return r;
}
static __device__ __forceinline__ void gl16(const short* g, short* l) {
    __builtin_amdgcn_global_load_lds(
        (const __attribute__((address_space(1))) unsigned int*)g,
        (__attribute__((address_space(3))) unsigned int*)l, 16, 0, 0);
}

// ---------------------------------------------------------------------------
// prep: blocks [0,2048) split x; [2048,5120) transpose-split Wqkv;
//       [5120,6144) transpose-split Wout.
// ---------------------------------------------------------------------------
__global__ __launch_bounds__(256) void prep(
    const float* __restrict__ x, const float* __restrict__ Wqkv,
    const float* __restrict__ Wout,
    short* __restrict__ Xh, short* __restrict__ Xl,
    short* __restrict__ Wh, short* __restrict__ Wl,
    short* __restrict__ Woh, short* __restrict__ Wol)
{
    __shared__ float tile[32][33];
    const int bid = blockIdx.x;
    const int tid = threadIdx.x;

    if (bid < 2048) {                        // ---- split x ----
        const int i = (bid * 256 + tid) * 8;
        const float8 v = *(const float8*)&x[i];
        short8 h, l;
#pragma unroll
        for (int j = 0; j < 8; ++j) {
            h[j] = f2bf(v[j]);
            l[j] = f2bf(v[j] - bf2f(h[j]));
        }
        *(short8*)&Xh[i] = h;
        *(short8*)&Xl[i] = l;
        return;
    }

    // ---- transpose + split a weight matrix ----
    const float* in; short *hi, *lo; int K, N, bx, by;
    if (bid < 5120) {
        const int b2 = bid - 2048;
        in = Wqkv; hi = Wh; lo = Wl; K = D_MODEL; N = N3;
        bx = b2 % 96; by = b2 / 96;
    } else {
        const int b3 = bid - 5120;
        in = Wout; hi = Woh; lo = Wol; K = D_MODEL; N = D_MODEL;
        bx = b3 & 31; by = b3 >> 5;
    }
    const int n0 = bx * 32, k0 = by * 32;
    const int tx = tid & 31, ty = tid >> 5;
#pragma unroll
    for (int i = 0; i < 4; ++i)
        tile[ty + 8*i][tx] = in[(k0 + ty + 8*i) * N + (n0 + tx)];
    __syncthreads();
#pragma unroll
    for (int i = 0; i < 4; ++i) {
        const float v  = tile[tx][ty + 8*i];
        const short vh = f2bf(v);
        const short vl = f2bf(v - bf2f(vh));
        const int idx  = (n0 + ty + 8*i) * K + (k0 + tx);
        hi[idx] = vh;
        lo[idx] = vl;
    }
}

// ---------------------------------------------------------------------------
// QKV GEMM, 8-phase schedule. BM=256 BN=192 BK=32, 512 threads (8 waves 2Mx4N),
// per-wave output 128x48. LDS: 2 x 56KB buffers, linear layout (gl16-direct,
// conflict-free contiguous ds_read). Prefetch tile t+1 issued at phase 0 of
// tile t; single vmcnt(0) drain per K-tile at phase 3.
// ---------------------------------------------------------------------------
#define QBUF_SH 28672          // shorts per LDS buffer (56KB)
#define OFF_AL  8192
#define OFF_BH  16384
#define OFF_BL  22528

__global__ __launch_bounds__(512, 2) void qkv_gemm8(
    const short* __restrict__ Xh, const short* __restrict__ Xl,
    const short* __restrict__ Bh, const short* __restrict__ Bl,
    const float* __restrict__ bias,
    short* __restrict__ Qo, short* __restrict__ Ko, short* __restrict__ Vt)
{
    __shared__ __attribute__((aligned(16))) short smem[2 * QBUF_SH];

    const int tid  = threadIdx.x;
    const int wave = tid >> 6, lane = tid & 63;
    const int q4 = lane >> 4, l16 = lane & 15;
    const int wr = wave >> 2, wc = wave & 3;

    const int flat = blockIdx.x;
    const int sw = (flat & 7) * 32 + (flat >> 3);
    const int mt = sw & 15, nt = sw >> 4;
    const int m0 = mt * 256, n0 = nt * 192;

    const short* srcp[7];
#pragma unroll
    for (int j = 0; j < 7; ++j) {
        const int id = j * 512 + tid;
        const short* s;
        if (id < 1024)      { s = &Xh[(size_t)(m0 + (id >> 2)) * D_MODEL + (id & 3) * 8]; }
        else if (id < 2048) { const int c = id - 1024; s = &Xl[(size_t)(m0 + (c >> 2)) * D_MODEL + (c & 3) * 8]; }
        else if (id < 2816) { const int c = id - 2048; s = &Bh[(size_t)(n0 + (c >> 2)) * D_MODEL + (c & 3) * 8]; }
        else                { const int c = id - 2816; s = &Bl[(size_t)(n0 + (c >> 2)) * D_MODEL + (c & 3) * 8]; }
        srcp[j] = s;
    }

    auto stage = [&](int b) {
#pragma unroll
        for (int j = 0; j < 7; ++j) {
            gl16(srcp[j], smem + b * QBUF_SH + (j * 512 + tid) * 8);
            srcp[j] += 32;                  // advance one K-tile
        }
    };

    f32x4 acc[8][3];
#pragma unroll
    for (int i = 0; i < 8; ++i)
#pragma unroll
        for (int j = 0; j < 3; ++j) acc[i][j] = (f32x4){0.f, 0.f, 0.f, 0.f};

    stage(0);
    asm volatile("s_waitcnt vmcnt(0)" ::: "memory");
    __builtin_amdgcn_s_barrier();

    for (int t = 0; t < 32; ++t) {
        const int cur = t & 1;
        const short* base = smem + cur * QBUF_SH;
        const short* Ah_s = base;
        const short* Al_s = base + OFF_AL;
        const short* Bh_s = base + OFF_BH;
        const short* Bl_s = base + OFF_BL;

        short8 bhf[3], blf[3];
#pragma unroll
        for (int p = 0; p < 4; ++p) {
            const int r0 = (wr * 128 + (2*p)   * 16 + l16) * 32 + q4 * 8;
            const int r1 = (wr * 128 + (2*p+1) * 16 + l16) * 32 + q4 * 8;
            const short8 a0h = *(const short8*)(Ah_s + r0);
            const short8 a0l = *(const short8*)(Al_s + r0);
            const short8 a1h = *(const short8*)(Ah_s + r1);
            const short8 a1l = *(const short8*)(Al_s + r1);
            if (p == 0) {
#pragma unroll
                for (int n = 0; n < 3; ++n) {
                    const int rb = (wc * 48 + n * 16 + l16) * 32 + q4 * 8;
                    bhf[n] = *(const short8*)(Bh_s + rb);
                    blf[n] = *(const short8*)(Bl_s + rb);
                }
                if (t < 31) stage(cur ^ 1);
            }
            __builtin_amdgcn_s_barrier();
            asm volatile("s_waitcnt lgkmcnt(0)" ::: "memory");
            __builtin_amdgcn_sched_barrier(0);
            __builtin_amdgcn_s_setprio(1);
#pragma unroll
            for (int n = 0; n < 3; ++n) {
                acc[2*p][n]   = __builtin_amdgcn_mfma_f32_16x16x32_bf16(a0h, bhf[n], acc[2*p][n],   0, 0, 0);
                acc[2*p][n]   = __builtin_amdgcn_mfma_f32_16x16x32_bf16(a0h, blf[n], acc[2*p][n],   0, 0, 0);
                acc[2*p][n]   = __builtin_amdgcn_mfma_f32_16x16x32_bf16(a0l, bhf[n], acc[2*p][n],   0, 0, 0);
                acc[2*p+1][n] = __builtin_amdgcn_mfma_f32_16x16x32_bf16(a1h, bhf[n], acc[2*p+1][n], 0, 0, 0);
                acc[2*p+1][n] = __builtin_amdgcn_mfma_f32_16x16x32_bf16(a1h, blf[n], acc[2*p+1][n], 0, 0, 0);
                acc[2*p+1][n] = __builtin_amdgcn_mfma_f32_16x16x32_bf16(a1l, bhf[n], acc[2*p+1][n], 0, 0, 0);
            }
            __builtin_amdgcn_s_setprio(0);
            if (p == 3) asm volatile("s_waitcnt vmcnt(0)" ::: "memory");
            __builtin_amdgcn_s_barrier();
        }
    }

    const float SCALE_Q = 0.125f * 1.4426950408889634f;
#pragma unroll
    for (int tj = 0; tj < 3; ++tj) {
        const int jj = wc * 48 + tj * 16 + l16;   // 0..191 within head
        const int n  = nt * 192 + jj;
        const float bv = bias[n];
#pragma unroll
        for (int ti = 0; ti < 8; ++ti) {
            const int mb = m0 + wr * 128 + ti * 16 + q4 * 4;
            const int b = mb >> 11;
            const int s = mb & 2047;
            const int bh_ = b * NHEAD + nt;
            if (jj >= 128) {                      // Vt: s is fast axis -> short4
                short4v v4;
#pragma unroll
                for (int r = 0; r < 4; ++r) v4[r] = f2bf(acc[ti][tj][r] + bv);
                *(short4v*)&Vt[(bh_ * HD + (jj - 128)) * SEQ + s] = v4;
            } else if (jj < 64) {
#pragma unroll
                for (int r = 0; r < 4; ++r)
                    Qo[(bh_ * SEQ + s + r) * HD + jj] = f2bf((acc[ti][tj][r] + bv) * SCALE_Q);
            } else {
#pragma unroll
                for (int r = 0; r < 4; ++r)
                    Ko[(bh_ * SEQ + s + r) * HD + (jj - 64)] = f2bf(acc[ti][tj][r] + bv);
            }
        }
    }
}

// ---------------------------------------------------------------------------
// Transposed-score flash attention. KVBLK=64, double-buffered K/V in LDS,
// async reg-staging (loads for tile t+1 issued at top of tile t), ONE barrier
// per 64 keys. Grid (32 bh, 16 qb); 4 waves x 32 queries.
// ---------------------------------------------------------------------------
__global__ __launch_bounds__(256, 2) void attn_tscore(
    const short* __restrict__ Q, const short* __restrict__ K,
    const short* __restrict__ Vt,
    short* __restrict__ Ch, short* __restrict__ Cl)
{
    __shared__ __attribute__((aligned(16))) char smem[36864];
    short (*Ks)[72] = (short(*)[72])smem;                 // [2*64 key][64 d + pad]
    short (*Vs)[72] = (short(*)[72])(smem + 18432);       // [2*64 d][64 key + pad]

    const int bh = blockIdx.x;                // 0..31
    const int qb = blockIdx.y;                // 0..15
    const int bi = bh >> 4, hi_ = bh & 15;

    const short* Qp  = Q  + bh * SEQ * HD;
    const short* Kp  = K  + bh * SEQ * HD;
    const short* Vtp = Vt + bh * HD * SEQ;

    const int tid  = threadIdx.x;
    const int wave = tid >> 6, lane = tid & 63;
    const int l5 = lane & 31, hf = lane >> 5;
    const int q0w = qb * 128 + wave * 32;

    short8 qf[4];
#pragma unroll
    for (int c = 0; c < 4; ++c)
        qf[c] = *(const short8*)&Qp[(q0w + l5) * HD + c * 16 + hf * 8];

    f32x16 oacc0 = (f32x16)(0.f), oacc1 = (f32x16)(0.f);
    float m = -1.0e30f, l = 0.f;

    // staging: 256 threads cover 64 rows x 64 cols (2x short8 each for K and V)
    const int sr = tid >> 2;          // 0..63
    const int sc = (tid & 3) * 16;    // 0,16,32,48

    short8 kr0 = *(const short8*)&Kp[sr * HD + sc];
    short8 kr1 = *(const short8*)&Kp[sr * HD + sc + 8];
    short8 vr0 = *(const short8*)&Vtp[sr * SEQ + sc];
    short8 vr1 = *(const short8*)&Vtp[sr * SEQ + sc + 8];
    *(short8*)&Ks[sr][sc]     = kr0;
    *(short8*)&Ks[sr][sc + 8] = kr1;
    *(short8*)&Vs[sr][sc]     = vr0;
    *(short8*)&Vs[sr][sc + 8] = vr1;
    __syncthreads();

    for (int kc = 0; kc < 32; ++kc) {
        const int buf = (kc & 1) << 6;

        // issue next tile's global loads (hidden under this tile's compute)
        if (kc < 31) {
            const int nkb = (kc + 1) << 6;
            kr0 = *(const short8*)&Kp[(nkb + sr) * HD + sc];
            kr1 = *(const short8*)&Kp[(nkb + sr) * HD + sc + 8];
            vr0 = *(const short8*)&Vtp[sr * SEQ + nkb + sc];
            vr1 = *(const short8*)&Vtp[sr * SEQ + nkb + sc + 8];
        }

        // ---- scores: two 32-key tiles ----
        f32x16 s0 = (f32x16)(0.f), s1 = (f32x16)(0.f);
#pragma unroll
        for (int c = 0; c < 4; ++c) {
            const short8 ka0 = *(const short8*)&Ks[buf + l5][c * 16 + hf * 8];
            const short8 ka1 = *(const short8*)&Ks[buf + 32 + l5][c * 16 + hf * 8];
            s0 = __builtin_amdgcn_mfma_f32_32x32x16_bf16(ka0, qf[c], s0, 0, 0, 0);
            s1 = __builtin_amdgcn_mfma_f32_32x32x16_bf16(ka1, qf[c], s1, 0, 0, 0);
        }

        // ---- row max over 32 scores/lane (+ cross-half) ----
        float t[8];
#pragma unroll
        for (int i = 0; i < 8; ++i)
            t[i] = fmaxf(fmaxf(s0[i], s0[i + 8]), fmaxf(s1[i], s1[i + 8]));
        float pmax = fmaxf(fmaxf(fmaxf(t[0], t[1]), fmaxf(t[2], t[3])),
                           fmaxf(fmaxf(t[4], t[5]), fmaxf(t[6], t[7])));
        pmax = fmaxf(pmax, __shfl_xor(pmax, 32, 64));

        // ---- defer-max (T13): rescale only when max grew past threshold ----
        if (!__all(pmax - m <= 8.0f)) {
            const float mnew  = fmaxf(m, pmax);
            const float alpha = exp2f(m - mnew);
#pragma unroll
            for (int i = 0; i < 16; ++i) { oacc0[i] *= alpha; oacc1[i] *= alpha; }
            l *= alpha;
            m = mnew;
        }

        // ---- P = exp2(S - m), row sum ----
        float p0[16], p1[16];
#pragma unroll
        for (int i = 0; i < 16; ++i) { p0[i] = exp2f(s0[i] - m); p1[i] = exp2f(s1[i] - m); }
        float sa = 0.f, sb = 0.f, sc_ = 0.f, sd = 0.f;
#pragma unroll
        for (int i = 0; i < 4; ++i) {
            sa += p0[i] + p0[i + 8];
            sb += p0[i + 4] + p0[i + 12];
            sc_ += p1[i] + p1[i + 8];
            sd += p1[i + 4] + p1[i + 12];
        }
        float rs = (sa + sb) + (sc_ + sd);
        rs += __shfl_xor(rs, 32, 64);
        l += rs;

        // ---- pack P -> 4 bf16 B-fragments (hw cvt_pk + cross-half shfl) ----
        unsigned u0 = cvtpk(p0[0],  p0[1]),  u1 = cvtpk(p0[2],  p0[3]);
        unsigned u2 = cvtpk(p0[4],  p0[5]),  u3 = cvtpk(p0[6],  p0[7]);
        unsigned u4 = cvtpk(p0[8],  p0[9]),  u5 = cvtpk(p0[10], p0[11]);
        unsigned u6 = cvtpk(p0[12], p0[13]), u7 = cvtpk(p0[14], p0[15]);
        unsigned w0 = cvtpk(p1[0],  p1[1]),  w1 = cvtpk(p1[2],  p1[3]);
        unsigned w2 = cvtpk(p1[4],  p1[5]),  w3 = cvtpk(p1[6],  p1[7]);
        unsigned w4 = cvtpk(p1[8],  p1[9]),  w5 = cvtpk(p1[10], p1[11]);
        unsigned w6 = cvtpk(p1[12], p1[13]), w7 = cvtpk(p1[14], p1[15]);
        const unsigned x0 = __shfl_xor(u0, 32, 64), x1 = __shfl_xor(u1, 32, 64);
        const unsigned x2 = __shfl_xor(u2, 32, 64), x3 = __shfl_xor(u3, 32, 64);
        const unsigned x4 = __shfl_xor(u4, 32, 64), x5 = __shfl_xor(u5, 32, 64);
        const unsigned x6 = __shfl_xor(u6, 32, 64), x7 = __shfl_xor(u7, 32, 64);
        const unsigned y0 = __shfl_xor(w0, 32, 64), y1 = __shfl_xor(w1, 32, 64);
        const unsigned y2 = __shfl_xor(w2, 32, 64), y3 = __shfl_xor(w3, 32, 64);
        const unsigned y4 = __shfl_xor(w4, 32, 64), y5 = __shfl_xor(w5, 32, 64);
        const unsigned y6 = __shfl_xor(w6, 32, 64), y7 = __shfl_xor(w7, 32, 64);
        int4v pb0 = (int4v){ (int)(hf ? x2 : u0), (int)(hf ? x3 : u1),
                             (int)(hf ? u2 : x0), (int)(hf ? u3 : x1) };
        int4v pb1 = (int4v){ (int)(hf ? x6 : u4), (int)(hf ? x7 : u5),
                             (int)(hf ? u6 : x4), (int)(hf ? u7 : x5) };
        int4v pb2 = (int4v){ (int)(hf ? y2 : w0), (int)(hf ? y3 : w1),
                             (int)(hf ? w2 : y0), (int)(hf ? w3 : y1) };
        int4v pb3 = (int4v){ (int)(hf ? y6 : w4), (int)(hf ? y7 : w5),
                             (int)(hf ? w6 : y4), (int)(hf ? w7 : y5) };
        const short8 pbf0 = __builtin_bit_cast(short8, pb0);
        const short8 pbf1 = __builtin_bit_cast(short8, pb1);
        const short8 pbf2 = __builtin_bit_cast(short8, pb2);
        const short8 pbf3 = __builtin_bit_cast(short8, pb3);

        // ---- PV: O += V[d][k-slice] . P ----
        {
            const short8 va0 = *(const short8*)&Vs[buf + l5][hf * 8];
            const short8 va1 = *(const short8*)&Vs[buf + l5][16 + hf * 8];
            const short8 va2 = *(const short8*)&Vs[buf + l5][32 + hf * 8];
            const short8 va3 = *(const short8*)&Vs[buf + l5][48 + hf * 8];
            oacc0 = __builtin_amdgcn_mfma_f32_32x32x16_bf16(va0, pbf0, oacc0, 0, 0, 0);
            oacc0 = __builtin_amdgcn_mfma_f32_32x32x16_bf16(va1, pbf1, oacc0, 0, 0, 0);
            oacc0 = __builtin_amdgcn_mfma_f32_32x32x16_bf16(va2, pbf2, oacc0, 0, 0, 0);
            oacc0 = __builtin_amdgcn_mfma_f32_32x32x16_bf16(va3, pbf3, oacc0, 0, 0, 0);
            const short8 vb0 = *(const short8*)&Vs[buf + 32 + l5][hf * 8];
            const short8 vb1 = *(const short8*)&Vs[buf + 32 + l5][16 + hf * 8];
            const short8 vb2 = *(const short8*)&Vs[buf + 32 + l5][32 + hf * 8];
            const short8 vb3 = *(const short8*)&Vs[buf + 32 + l5][48 + hf * 8];
            oacc1 = __builtin_amdgcn_mfma_f32_32x32x16_bf16(vb0, pbf0, oacc1, 0, 0, 0);
            oacc1 = __builtin_amdgcn_mfma_f32_32x32x16_bf16(vb1, pbf1, oacc1, 0, 0, 0);
            oacc1 = __builtin_amdgcn_mfma_f32_32x32x16_bf16(vb2, pbf2, oacc1, 0, 0, 0);
            oacc1 = __builtin_amdgcn_mfma_f32_32x32x16_bf16(vb3, pbf3, oacc1, 0, 0, 0);
        }

        // ---- write next tile into other buffer; one barrier per iter ----
        if (kc < 31) {
            const int wb = ((kc + 1) & 1) << 6;
            *(short8*)&Ks[wb + sr][sc]     = kr0;
            *(short8*)&Ks[wb + sr][sc + 8] = kr1;
            *(short8*)&Vs[wb + sr][sc]     = vr0;
            *(short8*)&Vs[wb + sr][sc + 8] = vr1;
        }
        __syncthreads();
    }

    // normalize (lane-scalar) then LDS transpose + split-bf16 ctx write
    const float inv = 1.0f / l;
#pragma unroll
    for (int i = 0; i < 16; ++i) { oacc0[i] *= inv; oacc1[i] *= inv; }

    float (*epi)[68] = (float(*)[68])(smem + wave * 8704);
#pragma unroll
    for (int r = 0; r < 16; ++r) {
        const int d = (r & 3) + 8 * (r >> 2) + 4 * hf;
        epi[l5][d]      = oacc0[r];
        epi[l5][32 + d] = oacc1[r];
    }
    __builtin_amdgcn_s_waitcnt(0);
#pragma unroll
    for (int pass = 0; pass < 8; ++pass) {
        const int row = pass * 4 + (lane >> 4);
        const int col = (lane & 15) * 4;
        const float4 v = *(const float4*)&epi[row][col];
        const float o[4] = {v.x, v.y, v.z, v.w};
        short4v hh, ll;
#pragma unroll
        for (int i = 0; i < 4; ++i) {
            hh[i] = f2bf(o[i]);
            ll[i] = f2bf(o[i] - bf2f(hh[i]));
        }
        const size_t co = ((size_t)(bi * SEQ + q0w + row)) * D_MODEL + hi_ * HD + col;
        *(short4v*)&Ch[co] = hh;
        *(short4v*)&Cl[co] = ll;
    }
}

// ---------------------------------------------------------------------------
// Output GEMM, 128x128 tile, global_load_lds, split-bf16 -> fp32 out.
// ---------------------------------------------------------------------------
__global__ __launch_bounds__(256) void out_gemm128(
    const short* __restrict__ Ah, const short* __restrict__ Al,
    const short* __restrict__ Bh, const short* __restrict__ Bl,
    const float* __restrict__ bias, float* __restrict__ out)
{
    __shared__ short AhS[128*32], AlS[128*32], BhS[128*32], BlS[128*32];

    const int tid  = threadIdx.x;
    const int wave = tid >> 6, lane = tid & 63;
    const int q4 = lane >> 4, l16 = lane & 15;
    const int m0 = blockIdx.y * 128, n0 = blockIdx.x * 128;
    const int rw = (wave & 1) * 64, cw = (wave >> 1) * 64;
    const int trow = tid >> 2;
    const int tcol = (tid & 3) * 8;

    f32x4 acc[4][4];
#pragma unroll
    for (int i = 0; i < 4; ++i)
#pragma unroll
        for (int j = 0; j < 4; ++j) acc[i][j] = (f32x4){0.f, 0.f, 0.f, 0.f};

    for (int kt = 0; kt < D_MODEL; kt += 32) {
        gl16(&Ah[(m0 + trow) * D_MODEL + kt + tcol],      AhS + tid * 8);
        gl16(&Ah[(m0 + 64 + trow) * D_MODEL + kt + tcol], AhS + 2048 + tid * 8);
        gl16(&Al[(m0 + trow) * D_MODEL + kt + tcol],      AlS + tid * 8);
        gl16(&Al[(m0 + 64 + trow) * D_MODEL + kt + tcol], AlS + 2048 + tid * 8);
        gl16(&Bh[(n0 + trow) * D_MODEL + kt + tcol],      BhS + tid * 8);
        gl16(&Bh[(n0 + 64 + trow) * D_MODEL + kt + tcol], BhS + 2048 + tid * 8);
        gl16(&Bl[(n0 + trow) * D_MODEL + kt + tcol],      BlS + tid * 8);
        gl16(&Bl[(n0 + 64 + trow) * D_MODEL + kt + tcol], BlS + 2048 + tid * 8);
        __syncthreads();

        short8 ah[4], al[4], bh[4], bl[4];
#pragma unroll
        for (int t = 0; t < 4; ++t) {
            ah[t] = *(const short8*)&AhS[(rw + t * 16 + l16) * 32 + q4 * 8];
            al[t] = *(const short8*)&AlS[(rw + t * 16 + l16) * 32 + q4 * 8];
            bh[t] = *(const short8*)&BhS[(cw + t * 16 + l16) * 32 + q4 * 8];
            bl[t] = *(const short8*)&BlS[(cw + t * 16 + l16) * 32 + q4 * 8];
        }
#pragma unroll
        for (int ti = 0; ti < 4; ++ti)
#pragma unroll
            for (int tj = 0; tj < 4; ++tj) {
                acc[ti][tj] = __builtin_amdgcn_mfma_f32_16x16x32_bf16(ah[ti], bh[tj], acc[ti][tj], 0, 0, 0);
                acc[ti][tj] = __builtin_amdgcn_mfma_f32_16x16x32_bf16(ah[ti], bl[tj], acc[ti][tj], 0, 0, 0);
                acc[ti][tj] = __builtin_amdgcn_mfma_f32_16x16x32_bf16(al[ti], bh[tj], acc[ti][tj], 0, 0, 0);
            }
        __syncthreads();
    }

#pragma unroll
    for (int tj = 0; tj < 4; ++tj) {
        const int n = n0 + cw + tj * 16 + l16;
        const float bv = bias[n];
#pragma unroll
        for (int ti = 0; ti < 4; ++ti) {
            const int mb = m0 + rw + ti * 16 + q4 * 4;
#pragma unroll
            for (int r = 0; r < 4; ++r)
                out[(mb + r) * D_MODEL + n] = acc[ti][tj][r] + bv;
        }
    }
}

// ---------------------------------------------------------------------------
extern "C" void kernel_launch(void* const* d_in, const int* in_sizes, int n_in,
                              void* d_out, int out_size, void* d_ws, size_t ws_size,
                              hipStream_t stream)
{
    const float* x    = (const float*)d_in[0];
    const float* Wqkv = (const float*)d_in[1];
    const float* bqkv = (const float*)d_in[2];
    const float* Wout = (const float*)d_in[3];
    const float* bout = (const float*)d_in[4];
    float* out = (float*)d_out;

    char* ws = (char*)d_ws;
    short* Qb  = (short*)(ws);                //  8 MB [32][2048][64] (pre-scaled)
    short* Kb  = (short*)(ws +  8*MB);        //  8 MB
    short* Vtb = (short*)(ws + 16*MB);        //  8 MB [32][64][2048]
    short* Woh = (short*)(ws + 24*MB);        //  2 MB Wout^T hi
    short* Wol = (short*)(ws + 26*MB);        //  2 MB Wout^T lo
    short* Ch  = (short*)(ws + 28*MB);        //  8 MB ctx hi
    short* Cl  = (short*)(ws + 36*MB);        //  8 MB ctx lo
    short* Xh  = (short*)(ws + 44*MB);        //  8 MB x hi
    short* Xl  = (short*)(ws + 52*MB);        //  8 MB x lo
    short* Wh  = (short*)(ws + 60*MB);        //  6 MB Wqkv^T hi
    short* Wl  = (short*)(ws + 66*MB);        //  6 MB Wqkv^T lo (end 72 MB)

    prep<<<6144, 256, 0, stream>>>(x, Wqkv, Wout, Xh, Xl, Wh, Wl, Woh, Wol);
    qkv_gemm8<<<dim3(256), 512, 0, stream>>>(Xh, Xl, Wh, Wl, bqkv, Qb, Kb, Vtb);
    attn_tscore<<<dim3(32, 16), 256, 0, stream>>>(Qb, Kb, Vtb, Ch, Cl);
    out_gemm128<<<dim3(8, 32), 256, 0, stream>>>(Ch, Cl, Woh, Wol, bout, out);
}

// Round 3
// 276.145 us; speedup vs baseline: 1.1527x; 1.0144x over previous
//
#include <hip/hip_runtime.h>

// ---------------------------------------------------------------------------
// MultiHeadAttention, fp32 in/out. 4-kernel pipeline:
//   prep      : Wqkv^T/Wout^T transpose+split-bf16, x split-bf16 (fused)
//   qkv_gemm8 : 256x192 split-bf16 MFMA, 2-phase/K-tile schedule, XOR
//               bank-swizzle (source-side, LDS linear), global_load_lds
//               double-buffer; scatters Q,K,Vt bf16
//   attn      : transposed-score flash (S^T=K.Q^T, 32x32x16), KVBLK=64,
//               double-buffered K/V LDS with async reg-staging (T14),
//               hw cvt_pk P-pack, defer-max (T13); split-bf16 ctx out
//   out_gemm  : 128x128 split-bf16 MFMA + XOR bank-swizzle -> fp32 out
// ---------------------------------------------------------------------------

typedef __attribute__((ext_vector_type(8)))  short short8;
typedef __attribute__((ext_vector_type(4)))  short short4v;
typedef __attribute__((ext_vector_type(8)))  float float8;
typedef __attribute__((ext_vector_type(4)))  float f32x4;
typedef __attribute__((ext_vector_type(16))) float f32x16;
typedef __attribute__((ext_vector_type(4)))  int   int4v;

#define D_MODEL 1024
#define NHEAD   16
#define HD      64
#define SEQ     2048
#define N3      (3*D_MODEL)
#define MB      (1024*1024)

static __device__ __forceinline__ float bf2f(short s) {
    unsigned u = ((unsigned)(unsigned short)s) << 16;
    return __builtin_bit_cast(float, u);
}
static __device__ __forceinline__ short f2bf(float f) {
    unsigned u = __builtin_bit_cast(unsigned, f);
    u = (u + 0x7fff + ((u >> 16) & 1)) >> 16;   // RNE
    return (short)u;
}
// hardware packed f32->bf16 (RNE), 1 instr
static __device__ __forceinline__ unsigned cvtpk(float a, float b) {
    unsigned r;
    asm("v_cvt_pk_bf16_f32 %0, %1, %2" : "=v"(r) : "v"(a), "v"(b));
    return r;
}
static __device__ __forceinline__ void gl16(const short* g, short* l) {
    __builtin_amdgcn_global_load_lds(
        (const __attribute__((address_space(1))) unsigned int*)g,
        (__attribute__((address_space(3))) unsigned int*)l, 16, 0, 0);
}

// ---------------------------------------------------------------------------
// prep: blocks [0,2048) split x; [2048,5120) transpose-split Wqkv;
//       [5120,6144) transpose-split Wout.
// ---------------------------------------------------------------------------
__global__ __launch_bounds__(256) void prep(
    const float* __restrict__ x, const float* __restrict__ Wqkv,
    const float* __restrict__ Wout,
    short* __restrict__ Xh, short* __restrict__ Xl,
    short* __restrict__ Wh, short* __restrict__ Wl,
    short* __restrict__ Woh, short* __restrict__ Wol)
{
    __shared__ float tile[32][33];
    const int bid = blockIdx.x;
    const int tid = threadIdx.x;

    if (bid < 2048) {                        // ---- split x ----
        const int i = (bid * 256 + tid) * 8;
        const float8 v = *(const float8*)&x[i];
        short8 h, l;
#pragma unroll
        for (int j = 0; j < 8; ++j) {
            h[j] = f2bf(v[j]);
            l[j] = f2bf(v[j] - bf2f(h[j]));
        }
        *(short8*)&Xh[i] = h;
        *(short8*)&Xl[i] = l;
        return;
    }

    // ---- transpose + split a weight matrix ----
    const float* in; short *hi, *lo; int K, N, bx, by;
    if (bid < 5120) {
        const int b2 = bid - 2048;
        in = Wqkv; hi = Wh; lo = Wl; K = D_MODEL; N = N3;
        bx = b2 % 96; by = b2 / 96;
    } else {
        const int b3 = bid - 5120;
        in = Wout; hi = Woh; lo = Wol; K = D_MODEL; N = D_MODEL;
        bx = b3 & 31; by = b3 >> 5;
    }
    const int n0 = bx * 32, k0 = by * 32;
    const int tx = tid & 31, ty = tid >> 5;
#pragma unroll
    for (int i = 0; i < 4; ++i)
        tile[ty + 8*i][tx] = in[(k0 + ty + 8*i) * N + (n0 + tx)];
    __syncthreads();
#pragma unroll
    for (int i = 0; i < 4; ++i) {
        const float v  = tile[tx][ty + 8*i];
        const short vh = f2bf(v);
        const short vl = f2bf(v - bf2f(vh));
        const int idx  = (n0 + ty + 8*i) * K + (k0 + tx);
        hi[idx] = vh;
        lo[idx] = vl;
    }
}

// ---------------------------------------------------------------------------
// QKV GEMM. BM=256 BN=192 BK=32, 512 threads (8 waves 2Mx4N), per-wave
// output 128x48. 2 phases per K-tile (4 barriers, 36 MFMA each) to match the
// proven 1-barrier-per-K=8 density. XOR bank-swizzle: LDS stays LINEAR
// (gl16-compatible); the global SOURCE chunk and the ds_read chunk are both
// permuted by the involution chunk ^= (row ^ (row>>2)) & 3, which spreads the
// former 8-way bank collision to 2 lanes/bank-set (free).
// ---------------------------------------------------------------------------
#define QBUF_SH 28672          // shorts per LDS buffer (56KB)
#define OFF_AL  8192
#define OFF_BH  16384
#define OFF_BL  22528

__global__ __launch_bounds__(512, 2) void qkv_gemm8(
    const short* __restrict__ Xh, const short* __restrict__ Xl,
    const short* __restrict__ Bh, const short* __restrict__ Bl,
    const float* __restrict__ bias,
    short* __restrict__ Qo, short* __restrict__ Ko, short* __restrict__ Vt)
{
    __shared__ __attribute__((aligned(16))) short smem[2 * QBUF_SH];

    const int tid  = threadIdx.x;
    const int wave = tid >> 6, lane = tid & 63;
    const int q4 = lane >> 4, l16 = lane & 15;
    const int wr = wave >> 2, wc = wave & 3;
    // swizzled chunk offset for all fragment reads (involution in l16 only:
    // row_rel & 3 == l16 & 3 and (row_rel>>2) & 3 == (l16>>2) & 3 for every
    // fragment row this kernel reads)
    const int csw = (q4 ^ ((l16 ^ (l16 >> 2)) & 3)) * 8;

    const int flat = blockIdx.x;
    const int sw = (flat & 7) * 32 + (flat >> 3);
    const int mt = sw & 15, nt = sw >> 4;
    const int m0 = mt * 256, n0 = nt * 192;

    // staging map: flat chunk id = j*512+tid over [Ah 1024][Al 1024][Bh 768][Bl 768]
    // source chunk column is pre-swizzled so the linear LDS write lands swizzled
    const short* srcp[7];
#pragma unroll
    for (int j = 0; j < 7; ++j) {
        const int id = j * 512 + tid;
        int r; const short* mat; int row0;
        if (id < 1024)      { r = id >> 2;          mat = Xh; row0 = m0; }
        else if (id < 2048) { r = (id - 1024) >> 2; mat = Xl; row0 = m0; }
        else if (id < 2816) { r = (id - 2048) >> 2; mat = Bh; row0 = n0; }
        else                { r = (id - 2816) >> 2; mat = Bl; row0 = n0; }
        const int cg = (id & 3) ^ ((r ^ (r >> 2)) & 3);
        srcp[j] = &mat[(size_t)(row0 + r) * D_MODEL + cg * 8];
    }

    auto stage = [&](int b) {
#pragma unroll
        for (int j = 0; j < 7; ++j) {
            gl16(srcp[j], smem + b * QBUF_SH + (j * 512 + tid) * 8);
            srcp[j] += 32;                  // advance one K-tile
        }
    };

    f32x4 acc[8][3];
#pragma unroll
    for (int i = 0; i < 8; ++i)
#pragma unroll
        for (int j = 0; j < 3; ++j) acc[i][j] = (f32x4){0.f, 0.f, 0.f, 0.f};

    stage(0);
    asm volatile("s_waitcnt vmcnt(0)" ::: "memory");
    __builtin_amdgcn_s_barrier();

    for (int t = 0; t < 32; ++t) {
        const int cur = t & 1;
        const short* base = smem + cur * QBUF_SH;
        const short* Ah_s = base;
        const short* Al_s = base + OFF_AL;
        const short* Bh_s = base + OFF_BH;
        const short* Bl_s = base + OFF_BL;

        // ---- phase 0: B frags + A frags ti=0..3; prefetch next K-tile ----
        short8 bhf[3], blf[3], a0h[4], a0l[4];
#pragma unroll
        for (int n = 0; n < 3; ++n) {
            const int rb = (wc * 48 + n * 16 + l16) * 32 + csw;
            bhf[n] = *(const short8*)(Bh_s + rb);
            blf[n] = *(const short8*)(Bl_s + rb);
        }
#pragma unroll
        for (int ti = 0; ti < 4; ++ti) {
            const int ra = (wr * 128 + ti * 16 + l16) * 32 + csw;
            a0h[ti] = *(const short8*)(Ah_s + ra);
            a0l[ti] = *(const short8*)(Al_s + ra);
        }
        if (t < 31) stage(cur ^ 1);         // stays in flight across barriers
        __builtin_amdgcn_s_barrier();
        asm volatile("s_waitcnt lgkmcnt(0)" ::: "memory");
        __builtin_amdgcn_sched_barrier(0);
        // early-issue phase-1 A frags (complete under phase-0 MFMA)
        short8 a1h[4], a1l[4];
#pragma unroll
        for (int ti = 0; ti < 4; ++ti) {
            const int ra = (wr * 128 + (4 + ti) * 16 + l16) * 32 + csw;
            a1h[ti] = *(const short8*)(Ah_s + ra);
            a1l[ti] = *(const short8*)(Al_s + ra);
        }
        __builtin_amdgcn_sched_barrier(0);
        __builtin_amdgcn_s_setprio(1);
#pragma unroll
        for (int ti = 0; ti < 4; ++ti)
#pragma unroll
            for (int n = 0; n < 3; ++n) {
                acc[ti][n] = __builtin_amdgcn_mfma_f32_16x16x32_bf16(a0h[ti], bhf[n], acc[ti][n], 0, 0, 0);
                acc[ti][n] = __builtin_amdgcn_mfma_f32_16x16x32_bf16(a0h[ti], blf[n], acc[ti][n], 0, 0, 0);
                acc[ti][n] = __builtin_amdgcn_mfma_f32_16x16x32_bf16(a0l[ti], bhf[n], acc[ti][n], 0, 0, 0);
            }
        __builtin_amdgcn_s_setprio(0);
        __builtin_amdgcn_s_barrier();

        // ---- phase 1: A frags ti=4..7 (already in flight) ----
        asm volatile("s_waitcnt lgkmcnt(0)" ::: "memory");
        __builtin_amdgcn_sched_barrier(0);
        __builtin_amdgcn_s_setprio(1);
#pragma unroll
        for (int ti = 0; ti < 4; ++ti)
#pragma unroll
            for (int n = 0; n < 3; ++n) {
                acc[4+ti][n] = __builtin_amdgcn_mfma_f32_16x16x32_bf16(a1h[ti], bhf[n], acc[4+ti][n], 0, 0, 0);
                acc[4+ti][n] = __builtin_amdgcn_mfma_f32_16x16x32_bf16(a1h[ti], blf[n], acc[4+ti][n], 0, 0, 0);
                acc[4+ti][n] = __builtin_amdgcn_mfma_f32_16x16x32_bf16(a1l[ti], bhf[n], acc[4+ti][n], 0, 0, 0);
            }
        __builtin_amdgcn_s_setprio(0);
        asm volatile("s_waitcnt vmcnt(0)" ::: "memory");
        __builtin_amdgcn_s_barrier();
    }

    // epilogue: scatter Q (pre-scaled), K, Vt
    const float SCALE_Q = 0.125f * 1.4426950408889634f;
#pragma unroll
    for (int tj = 0; tj < 3; ++tj) {
        const int jj = wc * 48 + tj * 16 + l16;   // 0..191 within head
        const int n  = nt * 192 + jj;
        const float bv = bias[n];
#pragma unroll
        for (int ti = 0; ti < 8; ++ti) {
            const int mb = m0 + wr * 128 + ti * 16 + q4 * 4;
            const int b = mb >> 11;
            const int s = mb & 2047;
            const int bh_ = b * NHEAD + nt;
            if (jj >= 128) {                      // Vt: s is fast axis -> short4
                short4v v4;
#pragma unroll
                for (int r = 0; r < 4; ++r) v4[r] = f2bf(acc[ti][tj][r] + bv);
                *(short4v*)&Vt[(bh_ * HD + (jj - 128)) * SEQ + s] = v4;
            } else if (jj < 64) {
#pragma unroll
                for (int r = 0; r < 4; ++r)
                    Qo[(bh_ * SEQ + s + r) * HD + jj] = f2bf((acc[ti][tj][r] + bv) * SCALE_Q);
            } else {
#pragma unroll
                for (int r = 0; r < 4; ++r)
                    Ko[(bh_ * SEQ + s + r) * HD + (jj - 64)] = f2bf(acc[ti][tj][r] + bv);
            }
        }
    }
}

// ---------------------------------------------------------------------------
// Transposed-score flash attention. KVBLK=64, double-buffered K/V in LDS,
// async reg-staging (loads for tile t+1 issued at top of tile t), ONE barrier
// per 64 keys. Grid (32 bh, 16 qb); 4 waves x 32 queries.
// ---------------------------------------------------------------------------
__global__ __launch_bounds__(256, 2) void attn_tscore(
    const short* __restrict__ Q, const short* __restrict__ K,
    const short* __restrict__ Vt,
    short* __restrict__ Ch, short* __restrict__ Cl)
{
    __shared__ __attribute__((aligned(16))) char smem[36864];
    short (*Ks)[72] = (short(*)[72])smem;                 // [2*64 key][64 d + pad]
    short (*Vs)[72] = (short(*)[72])(smem + 18432);       // [2*64 d][64 key + pad]

    const int bh = blockIdx.x;                // 0..31
    const int qb = blockIdx.y;                // 0..15
    const int bi = bh >> 4, hi_ = bh & 15;

    const short* Qp  = Q  + bh * SEQ * HD;
    const short* Kp  = K  + bh * SEQ * HD;
    const short* Vtp = Vt + bh * HD * SEQ;

    const int tid  = threadIdx.x;
    const int wave = tid >> 6, lane = tid & 63;
    const int l5 = lane & 31, hf = lane >> 5;
    const int q0w = qb * 128 + wave * 32;

    short8 qf[4];
#pragma unroll
    for (int c = 0; c < 4; ++c)
        qf[c] = *(const short8*)&Qp[(q0w + l5) * HD + c * 16 + hf * 8];

    f32x16 oacc0 = (f32x16)(0.f), oacc1 = (f32x16)(0.f);
    float m = -1.0e30f, l = 0.f;

    // staging: 256 threads cover 64 rows x 64 cols (2x short8 each for K and V)
    const int sr = tid >> 2;          // 0..63
    const int sc = (tid & 3) * 16;    // 0,16,32,48

    short8 kr0 = *(const short8*)&Kp[sr * HD + sc];
    short8 kr1 = *(const short8*)&Kp[sr * HD + sc + 8];
    short8 vr0 = *(const short8*)&Vtp[sr * SEQ + sc];
    short8 vr1 = *(const short8*)&Vtp[sr * SEQ + sc + 8];
    *(short8*)&Ks[sr][sc]     = kr0;
    *(short8*)&Ks[sr][sc + 8] = kr1;
    *(short8*)&Vs[sr][sc]     = vr0;
    *(short8*)&Vs[sr][sc + 8] = vr1;
    __syncthreads();

    for (int kc = 0; kc < 32; ++kc) {
        const int buf = (kc & 1) << 6;

        // issue next tile's global loads (hidden under this tile's compute)
        if (kc < 31) {
            const int nkb = (kc + 1) << 6;
            kr0 = *(const short8*)&Kp[(nkb + sr) * HD + sc];
            kr1 = *(const short8*)&Kp[(nkb + sr) * HD + sc + 8];
            vr0 = *(const short8*)&Vtp[sr * SEQ + nkb + sc];
            vr1 = *(const short8*)&Vtp[sr * SEQ + nkb + sc + 8];
        }

        // ---- scores: two 32-key tiles ----
        f32x16 s0 = (f32x16)(0.f), s1 = (f32x16)(0.f);
#pragma unroll
        for (int c = 0; c < 4; ++c) {
            const short8 ka0 = *(const short8*)&Ks[buf + l5][c * 16 + hf * 8];
            const short8 ka1 = *(const short8*)&Ks[buf + 32 + l5][c * 16 + hf * 8];
            s0 = __builtin_amdgcn_mfma_f32_32x32x16_bf16(ka0, qf[c], s0, 0, 0, 0);
            s1 = __builtin_amdgcn_mfma_f32_32x32x16_bf16(ka1, qf[c], s1, 0, 0, 0);
        }

        // ---- row max over 32 scores/lane (+ cross-half) ----
        float t[8];
#pragma unroll
        for (int i = 0; i < 8; ++i)
            t[i] = fmaxf(fmaxf(s0[i], s0[i + 8]), fmaxf(s1[i], s1[i + 8]));
        float pmax = fmaxf(fmaxf(fmaxf(t[0], t[1]), fmaxf(t[2], t[3])),
                           fmaxf(fmaxf(t[4], t[5]), fmaxf(t[6], t[7])));
        pmax = fmaxf(pmax, __shfl_xor(pmax, 32, 64));

        // ---- defer-max (T13): rescale only when max grew past threshold ----
        if (!__all(pmax - m <= 8.0f)) {
            const float mnew  = fmaxf(m, pmax);
            const float alpha = exp2f(m - mnew);
#pragma unroll
            for (int i = 0; i < 16; ++i) { oacc0[i] *= alpha; oacc1[i] *= alpha; }
            l *= alpha;
            m = mnew;
        }

        // ---- P = exp2(S - m), row sum ----
        float p0[16], p1[16];
#pragma unroll
        for (int i = 0; i < 16; ++i) { p0[i] = exp2f(s0[i] - m); p1[i] = exp2f(s1[i] - m); }
        float sa = 0.f, sb = 0.f, sc_ = 0.f, sd = 0.f;
#pragma unroll
        for (int i = 0; i < 4; ++i) {
            sa += p0[i] + p0[i + 8];
            sb += p0[i + 4] + p0[i + 12];
            sc_ += p1[i] + p1[i + 8];
            sd += p1[i + 4] + p1[i + 12];
        }
        float rs = (sa + sb) + (sc_ + sd);
        rs += __shfl_xor(rs, 32, 64);
        l += rs;

        // ---- pack P -> 4 bf16 B-fragments (hw cvt_pk + cross-half shfl) ----
        unsigned u0 = cvtpk(p0[0],  p0[1]),  u1 = cvtpk(p0[2],  p0[3]);
        unsigned u2 = cvtpk(p0[4],  p0[5]),  u3 = cvtpk(p0[6],  p0[7]);
        unsigned u4 = cvtpk(p0[8],  p0[9]),  u5 = cvtpk(p0[10], p0[11]);
        unsigned u6 = cvtpk(p0[12], p0[13]), u7 = cvtpk(p0[14], p0[15]);
        unsigned w0 = cvtpk(p1[0],  p1[1]),  w1 = cvtpk(p1[2],  p1[3]);
        unsigned w2 = cvtpk(p1[4],  p1[5]),  w3 = cvtpk(p1[6],  p1[7]);
        unsigned w4 = cvtpk(p1[8],  p1[9]),  w5 = cvtpk(p1[10], p1[11]);
        unsigned w6 = cvtpk(p1[12], p1[13]), w7 = cvtpk(p1[14], p1[15]);
        const unsigned x0 = __shfl_xor(u0, 32, 64), x1 = __shfl_xor(u1, 32, 64);
        const unsigned x2 = __shfl_xor(u2, 32, 64), x3 = __shfl_xor(u3, 32, 64);
        const unsigned x4 = __shfl_xor(u4, 32, 64), x5 = __shfl_xor(u5, 32, 64);
        const unsigned x6 = __shfl_xor(u6, 32, 64), x7 = __shfl_xor(u7, 32, 64);
        const unsigned y0 = __shfl_xor(w0, 32, 64), y1 = __shfl_xor(w1, 32, 64);
        const unsigned y2 = __shfl_xor(w2, 32, 64), y3 = __shfl_xor(w3, 32, 64);
        const unsigned y4 = __shfl_xor(w4, 32, 64), y5 = __shfl_xor(w5, 32, 64);
        const unsigned y6 = __shfl_xor(w6, 32, 64), y7 = __shfl_xor(w7, 32, 64);
        int4v pb0 = (int4v){ (int)(hf ? x2 : u0), (int)(hf ? x3 : u1),
                             (int)(hf ? u2 : x0), (int)(hf ? u3 : x1) };
        int4v pb1 = (int4v){ (int)(hf ? x6 : u4), (int)(hf ? x7 : u5),
                             (int)(hf ? u6 : x4), (int)(hf ? u7 : x5) };
        int4v pb2 = (int4v){ (int)(hf ? y2 : w0), (int)(hf ? y3 : w1),
                             (int)(hf ? w2 : y0), (int)(hf ? w3 : y1) };
        int4v pb3 = (int4v){ (int)(hf ? y6 : w4), (int)(hf ? y7 : w5),
                             (int)(hf ? w6 : y4), (int)(hf ? w7 : y5) };
        const short8 pbf0 = __builtin_bit_cast(short8, pb0);
        const short8 pbf1 = __builtin_bit_cast(short8, pb1);
        const short8 pbf2 = __builtin_bit_cast(short8, pb2);
        const short8 pbf3 = __builtin_bit_cast(short8, pb3);

        // ---- PV: O += V[d][k-slice] . P ----
        {
            const short8 va0 = *(const short8*)&Vs[buf + l5][hf * 8];
            const short8 va1 = *(const short8*)&Vs[buf + l5][16 + hf * 8];
            const short8 va2 = *(const short8*)&Vs[buf + l5][32 + hf * 8];
            const short8 va3 = *(const short8*)&Vs[buf + l5][48 + hf * 8];
            oacc0 = __builtin_amdgcn_mfma_f32_32x32x16_bf16(va0, pbf0, oacc0, 0, 0, 0);
            oacc0 = __builtin_amdgcn_mfma_f32_32x32x16_bf16(va1, pbf1, oacc0, 0, 0, 0);
            oacc0 = __builtin_amdgcn_mfma_f32_32x32x16_bf16(va2, pbf2, oacc0, 0, 0, 0);
            oacc0 = __builtin_amdgcn_mfma_f32_32x32x16_bf16(va3, pbf3, oacc0, 0, 0, 0);
            const short8 vb0 = *(const short8*)&Vs[buf + 32 + l5][hf * 8];
            const short8 vb1 = *(const short8*)&Vs[buf + 32 + l5][16 + hf * 8];
            const short8 vb2 = *(const short8*)&Vs[buf + 32 + l5][32 + hf * 8];
            const short8 vb3 = *(const short8*)&Vs[buf + 32 + l5][48 + hf * 8];
            oacc1 = __builtin_amdgcn_mfma_f32_32x32x16_bf16(vb0, pbf0, oacc1, 0, 0, 0);
            oacc1 = __builtin_amdgcn_mfma_f32_32x32x16_bf16(vb1, pbf1, oacc1, 0, 0, 0);
            oacc1 = __builtin_amdgcn_mfma_f32_32x32x16_bf16(vb2, pbf2, oacc1, 0, 0, 0);
            oacc1 = __builtin_amdgcn_mfma_f32_32x32x16_bf16(vb3, pbf3, oacc1, 0, 0, 0);
        }

        // ---- write next tile into other buffer; one barrier per iter ----
        if (kc < 31) {
            const int wb = ((kc + 1) & 1) << 6;
            *(short8*)&Ks[wb + sr][sc]     = kr0;
            *(short8*)&Ks[wb + sr][sc + 8] = kr1;
            *(short8*)&Vs[wb + sr][sc]     = vr0;
            *(short8*)&Vs[wb + sr][sc + 8] = vr1;
        }
        __syncthreads();
    }

    // normalize (lane-scalar) then LDS transpose + split-bf16 ctx write
    const float inv = 1.0f / l;
#pragma unroll
    for (int i = 0; i < 16; ++i) { oacc0[i] *= inv; oacc1[i] *= inv; }

    float (*epi)[68] = (float(*)[68])(smem + wave * 8704);
#pragma unroll
    for (int r = 0; r < 16; ++r) {
        const int d = (r & 3) + 8 * (r >> 2) + 4 * hf;
        epi[l5][d]      = oacc0[r];
        epi[l5][32 + d] = oacc1[r];
    }
    __builtin_amdgcn_s_waitcnt(0);
#pragma unroll
    for (int pass = 0; pass < 8; ++pass) {
        const int row = pass * 4 + (lane >> 4);
        const int col = (lane & 15) * 4;
        const float4 v = *(const float4*)&epi[row][col];
        const float o[4] = {v.x, v.y, v.z, v.w};
        short4v hh, ll;
#pragma unroll
        for (int i = 0; i < 4; ++i) {
            hh[i] = f2bf(o[i]);
            ll[i] = f2bf(o[i] - bf2f(hh[i]));
        }
        const size_t co = ((size_t)(bi * SEQ + q0w + row)) * D_MODEL + hi_ * HD + col;
        *(short4v*)&Ch[co] = hh;
        *(short4v*)&Cl[co] = ll;
    }
}

// ---------------------------------------------------------------------------
// Output GEMM, 128x128 tile, global_load_lds, split-bf16 -> fp32 out.
// Same XOR bank-swizzle as qkv (source-side + read-side, LDS linear).
// ---------------------------------------------------------------------------
__global__ __launch_bounds__(256) void out_gemm128(
    const short* __restrict__ Ah, const short* __restrict__ Al,
    const short* __restrict__ Bh, const short* __restrict__ Bl,
    const float* __restrict__ bias, float* __restrict__ out)
{
    __shared__ short AhS[128*32], AlS[128*32], BhS[128*32], BlS[128*32];

    const int tid  = threadIdx.x;
    const int wave = tid >> 6, lane = tid & 63;
    const int q4 = lane >> 4, l16 = lane & 15;
    const int m0 = blockIdx.y * 128, n0 = blockIdx.x * 128;
    const int rw = (wave & 1) * 64, cw = (wave >> 1) * 64;
    const int trow = tid >> 2;
    // source-side swizzle: store-chunk (tid&3) holds global chunk
    // (tid&3) ^ sw(trow); rows 64.. have the same sw since 64 = 0 (mod 4·4)
    const int tcol = (((tid & 3) ^ ((trow ^ (trow >> 2)) & 3))) * 8;
    // read-side swizzle (row_rel & 15 == l16 pattern for all frag rows)
    const int csw = (q4 ^ ((l16 ^ (l16 >> 2)) & 3)) * 8;

    f32x4 acc[4][4];
#pragma unroll
    for (int i = 0; i < 4; ++i)
#pragma unroll
        for (int j = 0; j < 4; ++j) acc[i][j] = (f32x4){0.f, 0.f, 0.f, 0.f};

    for (int kt = 0; kt < D_MODEL; kt += 32) {
        gl16(&Ah[(m0 + trow) * D_MODEL + kt + tcol],      AhS + tid * 8);
        gl16(&Ah[(m0 + 64 + trow) * D_MODEL + kt + tcol], AhS + 2048 + tid * 8);
        gl16(&Al[(m0 + trow) * D_MODEL + kt + tcol],      AlS + tid * 8);
        gl16(&Al[(m0 + 64 + trow) * D_MODEL + kt + tcol], AlS + 2048 + tid * 8);
        gl16(&Bh[(n0 + trow) * D_MODEL + kt + tcol],      BhS + tid * 8);
        gl16(&Bh[(n0 + 64 + trow) * D_MODEL + kt + tcol], BhS + 2048 + tid * 8);
        gl16(&Bl[(n0 + trow) * D_MODEL + kt + tcol],      BlS + tid * 8);
        gl16(&Bl[(n0 + 64 + trow) * D_MODEL + kt + tcol], BlS + 2048 + tid * 8);
        __syncthreads();

        short8 ah[4], al[4], bh[4], bl[4];
#pragma unroll
        for (int t = 0; t < 4; ++t) {
            const int ra = (rw + t * 16 + l16) * 32 + csw;
            const int rb = (cw + t * 16 + l16) * 32 + csw;
            ah[t] = *(const short8*)&AhS[ra];
            al[t] = *(const short8*)&AlS[ra];
            bh[t] = *(const short8*)&BhS[rb];
            bl[t] = *(const short8*)&BlS[rb];
        }
#pragma unroll
        for (int ti = 0; ti < 4; ++ti)
#pragma unroll
            for (int tj = 0; tj < 4; ++tj) {
                acc[ti][tj] = __builtin_amdgcn_mfma_f32_16x16x32_bf16(ah[ti], bh[tj], acc[ti][tj], 0, 0, 0);
                acc[ti][tj] = __builtin_amdgcn_mfma_f32_16x16x32_bf16(ah[ti], bl[tj], acc[ti][tj], 0, 0, 0);
                acc[ti][tj] = __builtin_amdgcn_mfma_f32_16x16x32_bf16(al[ti], bh[tj], acc[ti][tj], 0, 0, 0);
            }
        __syncthreads();
    }

#pragma unroll
    for (int tj = 0; tj < 4; ++tj) {
        const int n = n0 + cw + tj * 16 + l16;
        const float bv = bias[n];
#pragma unroll
        for (int ti = 0; ti < 4; ++ti) {
            const int mb = m0 + rw + ti * 16 + q4 * 4;
#pragma unroll
            for (int r = 0; r < 4; ++r)
                out[(mb + r) * D_MODEL + n] = acc[ti][tj][r] + bv;
        }
    }
}

// ---------------------------------------------------------------------------
extern "C" void kernel_launch(void* const* d_in, const int* in_sizes, int n_in,
                              void* d_out, int out_size, void* d_ws, size_t ws_size,
                              hipStream_t stream)
{
    const float* x    = (const float*)d_in[0];
    const float* Wqkv = (const float*)d_in[1];
    const float* bqkv = (const float*)d_in[2];
    const float* Wout = (const float*)d_in[3];
    const float* bout = (const float*)d_in[4];
    float* out = (float*)d_out;

    char* ws = (char*)d_ws;
    short* Qb  = (short*)(ws);                //  8 MB [32][2048][64] (pre-scaled)
    short* Kb  = (short*)(ws +  8*MB);        //  8 MB
    short* Vtb = (short*)(ws + 16*MB);        //  8 MB [32][64][2048]
    short* Woh = (short*)(ws + 24*MB);        //  2 MB Wout^T hi
    short* Wol = (short*)(ws + 26*MB);        //  2 MB Wout^T lo
    short* Ch  = (short*)(ws + 28*MB);        //  8 MB ctx hi
    short* Cl  = (short*)(ws + 36*MB);        //  8 MB ctx lo
    short* Xh  = (short*)(ws + 44*MB);        //  8 MB x hi
    short* Xl  = (short*)(ws + 52*MB);        //  8 MB x lo
    short* Wh  = (short*)(ws + 60*MB);        //  6 MB Wqkv^T hi
    short* Wl  = (short*)(ws + 66*MB);        //  6 MB Wqkv^T lo (end 72 MB)

    prep<<<6144, 256, 0, stream>>>(x, Wqkv, Wout, Xh, Xl, Wh, Wl, Woh, Wol);
    qkv_gemm8<<<dim3(256), 512, 0, stream>>>(Xh, Xl, Wh, Wl, bqkv, Qb, Kb, Vtb);
    attn_tscore<<<dim3(32, 16), 256, 0, stream>>>(Qb, Kb, Vtb, Ch, Cl);
    out_gemm128<<<dim3(8, 32), 256, 0, stream>>>(Ch, Cl, Woh, Wol, bout, out);
}